// Round 1
// baseline (344.737 us; speedup 1.0000x reference)
//
#include <hip/hip_runtime.h>

#define B 64
#define N 2048
#define E 32768
#define D 256
#define H 256
#define CH 8   // chunks for the gather kernel

// ---------------------------------------------------------------------------
// Kernel A: per-batch edge aggregation.
//   w[n]  = sum_{e: row[e] < L, col[e]==n} val[e]         (LDS only)
//   z[m]  = sum_{e: col[e]==m} w[row[e]] * val[e]         (-> global)
//   sw[b] = sum_n w[n]                                    (-> global)
// One block per batch; w,z live in LDS (2*8KB).
// ---------------------------------------------------------------------------
__global__ __launch_bounds__(1024) void edge_kernel(
    const int* __restrict__ adj_row, const int* __restrict__ adj_col,
    const float* __restrict__ adj_val, const int* __restrict__ cur_len,
    float* __restrict__ z_out, float* __restrict__ sw_out)
{
    __shared__ float w[N];
    __shared__ float zz[N];
    __shared__ float swred;
    const int b   = blockIdx.x;
    const int tid = threadIdx.x;
    const int L   = *cur_len;

    for (int i = tid; i < N; i += blockDim.x) { w[i] = 0.f; zz[i] = 0.f; }
    if (tid == 0) swred = 0.f;
    __syncthreads();

    const int base = b * E;
    // pass 1: w
    for (int e = tid; e < E; e += blockDim.x) {
        int r = adj_row[base + e];
        if (r < L) {
            atomicAdd(&w[adj_col[base + e]], adj_val[base + e]);
        }
    }
    __syncthreads();
    // pass 2: z
    for (int e = tid; e < E; e += blockDim.x) {
        float wv = w[adj_row[base + e]];
        if (wv != 0.f) {
            atomicAdd(&zz[adj_col[base + e]], wv * adj_val[base + e]);
        }
    }
    __syncthreads();
    // write z, reduce sw
    float part = 0.f;
    for (int i = tid; i < N; i += blockDim.x) {
        z_out[b * N + i] = zz[i];
        part += w[i];
    }
    for (int off = 32; off > 0; off >>= 1) part += __shfl_down(part, off, 64);
    if ((tid & 63) == 0) atomicAdd(&swred, part);
    __syncthreads();
    if (tid == 0) sw_out[b] = swred;
}

// ---------------------------------------------------------------------------
// Kernel B: u_part[b,chunk,:] = sum_{n in chunk} z[b,n] * emb[neighbors[b,n], :]
// Grid (B, CH), 256 threads. Each wave processes one emb row at a time:
// all 64 lanes share n (and the row index), lane = float4 offset -> coalesced.
// ---------------------------------------------------------------------------
__global__ __launch_bounds__(256) void gather_kernel(
    const int* __restrict__ neighbors, const float* __restrict__ emb,
    const float* __restrict__ z, float* __restrict__ u_part)
{
    const int b     = blockIdx.x;
    const int chunk = blockIdx.y;
    const int tid   = threadIdx.x;
    const int d4    = tid & 63;   // float4 index within row (lane)
    const int rg    = tid >> 6;   // which of 4 waves

    const float4* emb4 = (const float4*)emb;
    float4 acc = make_float4(0.f, 0.f, 0.f, 0.f);

    const int n0 = chunk * (N / CH);
    for (int n = n0 + rg; n < n0 + (N / CH); n += 4) {
        float zv = z[b * N + n];                 // wave-uniform broadcast
        if (zv != 0.f) {                         // wave-uniform branch
            long idx = (long)neighbors[b * N + n];
            float4 v = emb4[idx * (D / 4) + d4]; // coalesced 1KB row read
            acc.x += zv * v.x; acc.y += zv * v.y;
            acc.z += zv * v.z; acc.w += zv * v.w;
        }
    }

    __shared__ float4 red[256];
    red[tid] = acc;
    __syncthreads();
    if (tid < 64) {
        float4 a = red[tid], bb = red[tid + 64], c = red[tid + 128], d = red[tid + 192];
        float4 s = make_float4(a.x + bb.x + c.x + d.x,
                               a.y + bb.y + c.y + d.y,
                               a.z + bb.z + c.z + d.z,
                               a.w + bb.w + c.w + d.w);
        ((float4*)u_part)[(b * CH + chunk) * (D / 4) + tid] = s;
    }
}

// ---------------------------------------------------------------------------
// Kernel C: per-batch head.
//   u = sum_chunks u_part ; y = u@W1 + sw*b1 ; pooled = (y/L)@W2 + b2 ;
//   out = relu(pooled@fc1_w + fc1_b)
// One block per batch, 256 threads (thread = output column).
// ---------------------------------------------------------------------------
__global__ __launch_bounds__(256) void head_kernel(
    const float* __restrict__ u_part, const float* __restrict__ sw,
    const float* __restrict__ W1, const float* __restrict__ b1,
    const float* __restrict__ W2, const float* __restrict__ b2,
    const float* __restrict__ fc1_w, const float* __restrict__ fc1_b,
    const int* __restrict__ cur_len, float* __restrict__ out)
{
    const int b = blockIdx.x;
    const int t = threadIdx.x;
    __shared__ float su[D];
    __shared__ float sy[H];
    __shared__ float sp[H];

    float uacc = 0.f;
    for (int c = 0; c < CH; ++c) uacc += u_part[(b * CH + c) * D + t];
    su[t] = uacc;
    __syncthreads();

    float acc = sw[b] * b1[t];
    for (int d = 0; d < D; ++d) acc += su[d] * W1[d * H + t];
    sy[t] = acc;
    __syncthreads();

    const float invL = 1.f / (float)(*cur_len);
    acc = 0.f;
    for (int k = 0; k < H; ++k) acc += sy[k] * W2[k * H + t];
    sp[t] = acc * invL + b2[t];
    __syncthreads();

    acc = fc1_b[t];
    for (int k = 0; k < H; ++k) acc += sp[k] * fc1_w[k * H + t];
    out[b * H + t] = fmaxf(acc, 0.f);
}

extern "C" void kernel_launch(void* const* d_in, const int* in_sizes, int n_in,
                              void* d_out, int out_size, void* d_ws, size_t ws_size,
                              hipStream_t stream) {
    const int*   neighbors = (const int*)  d_in[0];
    const int*   adj_row   = (const int*)  d_in[1];
    const int*   adj_col   = (const int*)  d_in[2];
    const float* adj_val   = (const float*)d_in[3];
    const float* emb_table = (const float*)d_in[4];
    const float* W1        = (const float*)d_in[5];
    const float* b1        = (const float*)d_in[6];
    const float* W2        = (const float*)d_in[7];
    const float* b2        = (const float*)d_in[8];
    const float* fc1_w     = (const float*)d_in[9];
    const float* fc1_b     = (const float*)d_in[10];
    const int*   cur_len   = (const int*)  d_in[11];
    float*       out       = (float*)d_out;

    // workspace layout
    float* z_ws  = (float*)d_ws;               // B*N floats      (512 KB)
    float* sw_ws = z_ws + (size_t)B * N;       // B floats
    float* u_ws  = sw_ws + 64;                 // B*CH*D floats   (512 KB), 16B-aligned

    edge_kernel<<<B, 1024, 0, stream>>>(adj_row, adj_col, adj_val, cur_len, z_ws, sw_ws);
    gather_kernel<<<dim3(B, CH), 256, 0, stream>>>(neighbors, emb_table, z_ws, u_ws);
    head_kernel<<<B, 256, 0, stream>>>(u_ws, sw_ws, W1, b1, W2, b2, fc1_w, fc1_b, cur_len, out);
}

// Round 2
// 275.176 us; speedup vs baseline: 1.2528x; 1.2528x over previous
//
#include <hip/hip_runtime.h>

#define B 64
#define N 2048
#define E 32768
#define D 256
#define H 256
#define CH 32          // gather chunks per batch (grid B x CH = 2048 blocks)
#define SEG 16         // edge segments per batch (grid B x SEG = 1024 blocks)
#define EPB (E / SEG)  // 2048 edges per block

// ---------------------------------------------------------------------------
// Edge pass 1: w[b,n] = sum_{e: row<L, col==n} val   (LDS histogram -> global atomics)
//              sw[b]  = sum_{e: row<L} val
// ---------------------------------------------------------------------------
__global__ __launch_bounds__(256) void edge_w_kernel(
    const int* __restrict__ adj_row, const int* __restrict__ adj_col,
    const float* __restrict__ adj_val, const int* __restrict__ cur_len,
    float* __restrict__ w_out, float* __restrict__ sw_out)
{
    __shared__ float wloc[N];
    __shared__ float sred[4];
    const int b = blockIdx.x, seg = blockIdx.y, tid = threadIdx.x;
    const int L = *cur_len;

    for (int i = tid; i < N; i += 256) wloc[i] = 0.f;
    __syncthreads();

    const int base = b * E + seg * EPB;
    float svp = 0.f;
    for (int e = tid; e < EPB; e += 256) {
        int r = adj_row[base + e];
        if (r < L) {
            float v = adj_val[base + e];
            atomicAdd(&wloc[adj_col[base + e]], v);
            svp += v;
        }
    }
    __syncthreads();

    for (int i = tid; i < N; i += 256) {
        float v = wloc[i];
        if (v != 0.f) atomicAdd(&w_out[(size_t)b * N + i], v);
    }
    for (int off = 32; off; off >>= 1) svp += __shfl_down(svp, off, 64);
    if ((tid & 63) == 0) sred[tid >> 6] = svp;
    __syncthreads();
    if (tid == 0) atomicAdd(&sw_out[b], sred[0] + sred[1] + sred[2] + sred[3]);
}

// ---------------------------------------------------------------------------
// Edge pass 2: z[b,m] = sum_{e: col==m} w[b,row[e]] * val[e]   (over ALL edges)
// ---------------------------------------------------------------------------
__global__ __launch_bounds__(256) void edge_z_kernel(
    const int* __restrict__ adj_row, const int* __restrict__ adj_col,
    const float* __restrict__ adj_val, const float* __restrict__ w,
    float* __restrict__ z_out)
{
    __shared__ float zloc[N];
    const int b = blockIdx.x, seg = blockIdx.y, tid = threadIdx.x;

    for (int i = tid; i < N; i += 256) zloc[i] = 0.f;
    __syncthreads();

    const int base = b * E + seg * EPB;
    const float* wb = w + (size_t)b * N;
    for (int e = tid; e < EPB; e += 256) {
        float wv = wb[adj_row[base + e]];
        if (wv != 0.f) atomicAdd(&zloc[adj_col[base + e]], wv * adj_val[base + e]);
    }
    __syncthreads();

    for (int i = tid; i < N; i += 256) {
        float v = zloc[i];
        if (v != 0.f) atomicAdd(&z_out[(size_t)b * N + i], v);
    }
}

// ---------------------------------------------------------------------------
// Gather: u_part[b,chunk,:] = sum_{n in chunk} z[b,n] * emb[neighbors[b,n], :]
// Grid (B, CH=32) = 2048 blocks -> 8 blocks/CU (full wave occupancy).
// One wave per row-read: lane = float4 offset -> perfectly coalesced 1KB reads.
// ---------------------------------------------------------------------------
__global__ __launch_bounds__(256) void gather_kernel(
    const int* __restrict__ neighbors, const float* __restrict__ emb,
    const float* __restrict__ z, float* __restrict__ u_part)
{
    const int b = blockIdx.x, chunk = blockIdx.y, tid = threadIdx.x;
    const int lane = tid & 63, rg = tid >> 6;
    const float4* __restrict__ emb4 = (const float4*)emb;
    float4 acc = make_float4(0.f, 0.f, 0.f, 0.f);

    const int n0 = chunk * (N / CH);
    #pragma unroll 4
    for (int i = 0; i < (N / CH) / 4; ++i) {
        const int n = n0 + 4 * i + rg;
        const float zv = z[(size_t)b * N + n];
        const long idx = (long)neighbors[(size_t)b * N + n];
        const float4 v = emb4[idx * (D / 4) + lane];
        acc.x += zv * v.x; acc.y += zv * v.y;
        acc.z += zv * v.z; acc.w += zv * v.w;
    }

    __shared__ float4 red[256];
    red[tid] = acc;
    __syncthreads();
    if (tid < 64) {
        float4 a = red[tid], bb = red[tid + 64], c = red[tid + 128], d = red[tid + 192];
        float4 s = make_float4(a.x + bb.x + c.x + d.x, a.y + bb.y + c.y + d.y,
                               a.z + bb.z + c.z + d.z, a.w + bb.w + c.w + d.w);
        ((float4*)u_part)[((size_t)b * CH + chunk) * (D / 4) + tid] = s;
    }
}

// ---------------------------------------------------------------------------
// Head: u = sum_chunks u_part ; y = u@W1 + sw*b1 ; p = y@W2/L + b2 ;
//       out = relu(p@fc1_w + fc1_b).  One block/batch, thread = out column.
// ---------------------------------------------------------------------------
__global__ __launch_bounds__(256) void head_kernel(
    const float* __restrict__ u_part, const float* __restrict__ sw,
    const float* __restrict__ W1, const float* __restrict__ b1,
    const float* __restrict__ W2, const float* __restrict__ b2,
    const float* __restrict__ fc1_w, const float* __restrict__ fc1_b,
    const int* __restrict__ cur_len, float* __restrict__ out)
{
    const int b = blockIdx.x, t = threadIdx.x;
    __shared__ float su[D];
    __shared__ float sy[H];
    __shared__ float sp[H];

    float uacc = 0.f;
    #pragma unroll 8
    for (int c = 0; c < CH; ++c) uacc += u_part[((size_t)b * CH + c) * D + t];
    su[t] = uacc;
    __syncthreads();

    float acc = sw[b] * b1[t];
    #pragma unroll 8
    for (int d = 0; d < D; ++d) acc += su[d] * W1[d * H + t];
    sy[t] = acc;
    __syncthreads();

    const float invL = 1.f / (float)(*cur_len);
    acc = 0.f;
    #pragma unroll 8
    for (int k = 0; k < H; ++k) acc += sy[k] * W2[k * H + t];
    sp[t] = acc * invL + b2[t];
    __syncthreads();

    acc = fc1_b[t];
    #pragma unroll 8
    for (int k = 0; k < H; ++k) acc += sp[k] * fc1_w[k * H + t];
    out[b * H + t] = fmaxf(acc, 0.f);
}

extern "C" void kernel_launch(void* const* d_in, const int* in_sizes, int n_in,
                              void* d_out, int out_size, void* d_ws, size_t ws_size,
                              hipStream_t stream) {
    const int*   neighbors = (const int*)  d_in[0];
    const int*   adj_row   = (const int*)  d_in[1];
    const int*   adj_col   = (const int*)  d_in[2];
    const float* adj_val   = (const float*)d_in[3];
    const float* emb_table = (const float*)d_in[4];
    const float* W1        = (const float*)d_in[5];
    const float* b1        = (const float*)d_in[6];
    const float* W2        = (const float*)d_in[7];
    const float* b2        = (const float*)d_in[8];
    const float* fc1_w     = (const float*)d_in[9];
    const float* fc1_b     = (const float*)d_in[10];
    const int*   cur_len   = (const int*)  d_in[11];
    float*       out       = (float*)d_out;

    // workspace layout (floats): [w: B*N][z: B*N][sw: 64][u: B*CH*D]
    float* w_ws  = (float*)d_ws;
    float* z_ws  = w_ws + (size_t)B * N;
    float* sw_ws = z_ws + (size_t)B * N;
    float* u_ws  = sw_ws + 64;                       // 16B-aligned

    // zero the atomic accumulation targets (w, z, sw)
    hipMemsetAsync(d_ws, 0, ((size_t)2 * B * N + 64) * sizeof(float), stream);

    edge_w_kernel<<<dim3(B, SEG), 256, 0, stream>>>(adj_row, adj_col, adj_val,
                                                    cur_len, w_ws, sw_ws);
    edge_z_kernel<<<dim3(B, SEG), 256, 0, stream>>>(adj_row, adj_col, adj_val,
                                                    w_ws, z_ws);
    gather_kernel<<<dim3(B, CH), 256, 0, stream>>>(neighbors, emb_table, z_ws, u_ws);
    head_kernel<<<B, 256, 0, stream>>>(u_ws, sw_ws, W1, b1, W2, b2,
                                       fc1_w, fc1_b, cur_len, out);
}

// Round 3
// 231.901 us; speedup vs baseline: 1.4866x; 1.1866x over previous
//
#include <hip/hip_runtime.h>

#define B 64
#define N 2048
#define E 32768
#define D 256
#define H 256
#define CH 32          // gather chunks per batch (grid B x CH = 2048 blocks)
#define SEG 8          // edge segments per batch (grid B x SEG = 512 blocks, 512 thr)
#define EPB (E / SEG)  // 4096 edges per block

// ---------------------------------------------------------------------------
// Edge pass 1: w[b,n] = sum_{e: row<L, col==n} val   (LDS histogram -> global atomics)
//              sw[b]  = sum_{e: row<L} val
// ---------------------------------------------------------------------------
__global__ __launch_bounds__(512) void edge_w_kernel(
    const int* __restrict__ adj_row, const int* __restrict__ adj_col,
    const float* __restrict__ adj_val, const int* __restrict__ cur_len,
    float* __restrict__ w_out, float* __restrict__ sw_out)
{
    __shared__ float wloc[N];
    __shared__ float sred[8];
    const int b = blockIdx.x, seg = blockIdx.y, tid = threadIdx.x;
    const int L = *cur_len;

    for (int i = tid; i < N; i += 512) wloc[i] = 0.f;
    __syncthreads();

    const int base = b * E + seg * EPB;
    float svp = 0.f;
    #pragma unroll
    for (int k = 0; k < EPB / 512; ++k) {
        const int e = base + tid + k * 512;
        const int r = adj_row[e];
        if (r < L) {
            const float v = adj_val[e];
            atomicAdd(&wloc[adj_col[e]], v);
            svp += v;
        }
    }
    __syncthreads();

    #pragma unroll
    for (int i = tid; i < N; i += 512) {
        const float v = wloc[i];
        if (v != 0.f) atomicAdd(&w_out[(size_t)b * N + i], v);
    }
    for (int off = 32; off; off >>= 1) svp += __shfl_down(svp, off, 64);
    if ((tid & 63) == 0) sred[tid >> 6] = svp;
    __syncthreads();
    if (tid == 0) {
        float s = 0.f;
        #pragma unroll
        for (int i = 0; i < 8; ++i) s += sred[i];
        atomicAdd(&sw_out[b], s);
    }
}

// ---------------------------------------------------------------------------
// Edge pass 2: z[b,m] = sum_{e: col==m} w[b,row[e]] * val[e]   (over ALL edges)
// ---------------------------------------------------------------------------
__global__ __launch_bounds__(512) void edge_z_kernel(
    const int* __restrict__ adj_row, const int* __restrict__ adj_col,
    const float* __restrict__ adj_val, const float* __restrict__ w,
    float* __restrict__ z_out)
{
    __shared__ float zloc[N];
    const int b = blockIdx.x, seg = blockIdx.y, tid = threadIdx.x;

    for (int i = tid; i < N; i += 512) zloc[i] = 0.f;
    __syncthreads();

    const int base = b * E + seg * EPB;
    const float* __restrict__ wb = w + (size_t)b * N;
    #pragma unroll
    for (int k = 0; k < EPB / 512; ++k) {
        const int e = base + tid + k * 512;
        const float wv = wb[adj_row[e]];
        if (wv != 0.f) atomicAdd(&zloc[adj_col[e]], wv * adj_val[e]);
    }
    __syncthreads();

    #pragma unroll
    for (int i = tid; i < N; i += 512) {
        const float v = zloc[i];
        if (v != 0.f) atomicAdd(&z_out[(size_t)b * N + i], v);
    }
}

// ---------------------------------------------------------------------------
// Gather: u_part[b,chunk,:] = sum_{n in chunk} z[b,n] * emb[neighbors[b,n], :]
// Grid (B, CH=32) = 2048 blocks -> 8 blocks/CU. One wave per row-read: lane =
// float4 offset -> coalesced 1KB reads. Two accumulators + unroll 8 for MLP.
// ---------------------------------------------------------------------------
__global__ __launch_bounds__(256) void gather_kernel(
    const int* __restrict__ neighbors, const float* __restrict__ emb,
    const float* __restrict__ z, float* __restrict__ u_part)
{
    const int b = blockIdx.x, chunk = blockIdx.y, tid = threadIdx.x;
    const int lane = tid & 63, rg = tid >> 6;
    const float4* __restrict__ emb4 = (const float4*)emb;
    float4 acc0 = make_float4(0.f, 0.f, 0.f, 0.f);
    float4 acc1 = make_float4(0.f, 0.f, 0.f, 0.f);

    const int n0 = chunk * (N / CH);
    #pragma unroll 8
    for (int i = 0; i < (N / CH) / 4; ++i) {      // 16 rows per wave
        const int n = n0 + 4 * i + rg;
        const float zv = z[(size_t)b * N + n];
        const long idx = (long)neighbors[(size_t)b * N + n];
        const float4 v = emb4[idx * (D / 4) + lane];
        if (i & 1) {
            acc1.x += zv * v.x; acc1.y += zv * v.y;
            acc1.z += zv * v.z; acc1.w += zv * v.w;
        } else {
            acc0.x += zv * v.x; acc0.y += zv * v.y;
            acc0.z += zv * v.z; acc0.w += zv * v.w;
        }
    }
    float4 acc = make_float4(acc0.x + acc1.x, acc0.y + acc1.y,
                             acc0.z + acc1.z, acc0.w + acc1.w);

    __shared__ float4 red[256];
    red[tid] = acc;
    __syncthreads();
    if (tid < 64) {
        float4 a = red[tid], bb = red[tid + 64], c = red[tid + 128], d = red[tid + 192];
        float4 s = make_float4(a.x + bb.x + c.x + d.x, a.y + bb.y + c.y + d.y,
                               a.z + bb.z + c.z + d.z, a.w + bb.w + c.w + d.w);
        ((float4*)u_part)[((size_t)b * CH + chunk) * (D / 4) + tid] = s;
    }
}

// ---------------------------------------------------------------------------
// Head: u = sum_chunks u_part ; y = u@W1 + sw*b1 ; p = y@W2/L + b2 ;
//       out = relu(p@fc1_w + fc1_b).
// 1024 threads: t = output col, s = 4-way k-split (serial chain 256 -> 64).
// ---------------------------------------------------------------------------
__global__ __launch_bounds__(1024) void head_kernel(
    const float* __restrict__ u_part, const float* __restrict__ sw,
    const float* __restrict__ W1, const float* __restrict__ b1,
    const float* __restrict__ W2, const float* __restrict__ b2,
    const float* __restrict__ fc1_w, const float* __restrict__ fc1_b,
    const int* __restrict__ cur_len, float* __restrict__ out)
{
    const int b = blockIdx.x;
    const int t = threadIdx.x & 255;   // output column
    const int s = threadIdx.x >> 8;    // k-split group (0..3)
    __shared__ float red[4][256];
    __shared__ float su[D];
    __shared__ float sy[H];
    __shared__ float sp[H];

    // u[t] = sum over 32 chunks of u_part  (each s-group sums 8 chunks)
    float part = 0.f;
    #pragma unroll
    for (int c = 0; c < 8; ++c)
        part += u_part[((size_t)b * CH + s * 8 + c) * D + t];
    red[s][t] = part;
    __syncthreads();
    if (s == 0) su[t] = red[0][t] + red[1][t] + red[2][t] + red[3][t];
    __syncthreads();

    // y = u@W1 + sw*b1
    part = 0.f;
    #pragma unroll 8
    for (int k = 0; k < 64; ++k) {
        const int d = s * 64 + k;
        part += su[d] * W1[d * H + t];
    }
    red[s][t] = part;
    __syncthreads();
    if (s == 0) sy[t] = red[0][t] + red[1][t] + red[2][t] + red[3][t] + sw[b] * b1[t];
    __syncthreads();

    // p = y@W2 / L + b2
    const float invL = 1.f / (float)(*cur_len);
    part = 0.f;
    #pragma unroll 8
    for (int k = 0; k < 64; ++k) {
        const int d = s * 64 + k;
        part += sy[d] * W2[d * H + t];
    }
    red[s][t] = part;
    __syncthreads();
    if (s == 0)
        sp[t] = (red[0][t] + red[1][t] + red[2][t] + red[3][t]) * invL + b2[t];
    __syncthreads();

    // out = relu(p@fc1_w + fc1_b)
    part = 0.f;
    #pragma unroll 8
    for (int k = 0; k < 64; ++k) {
        const int d = s * 64 + k;
        part += sp[d] * fc1_w[d * H + t];
    }
    red[s][t] = part;
    __syncthreads();
    if (s == 0) {
        const float v = red[0][t] + red[1][t] + red[2][t] + red[3][t] + fc1_b[t];
        out[(size_t)b * H + t] = fmaxf(v, 0.f);
    }
}

extern "C" void kernel_launch(void* const* d_in, const int* in_sizes, int n_in,
                              void* d_out, int out_size, void* d_ws, size_t ws_size,
                              hipStream_t stream) {
    const int*   neighbors = (const int*)  d_in[0];
    const int*   adj_row   = (const int*)  d_in[1];
    const int*   adj_col   = (const int*)  d_in[2];
    const float* adj_val   = (const float*)d_in[3];
    const float* emb_table = (const float*)d_in[4];
    const float* W1        = (const float*)d_in[5];
    const float* b1        = (const float*)d_in[6];
    const float* W2        = (const float*)d_in[7];
    const float* b2        = (const float*)d_in[8];
    const float* fc1_w     = (const float*)d_in[9];
    const float* fc1_b     = (const float*)d_in[10];
    const int*   cur_len   = (const int*)  d_in[11];
    float*       out       = (float*)d_out;

    // workspace layout (floats): [w: B*N][z: B*N][sw: 64][u: B*CH*D]
    float* w_ws  = (float*)d_ws;
    float* z_ws  = w_ws + (size_t)B * N;
    float* sw_ws = z_ws + (size_t)B * N;
    float* u_ws  = sw_ws + 64;                       // 16B-aligned

    // zero the atomic accumulation targets (w, z, sw)
    hipMemsetAsync(d_ws, 0, ((size_t)2 * B * N + 64) * sizeof(float), stream);

    edge_w_kernel<<<dim3(B, SEG), 512, 0, stream>>>(adj_row, adj_col, adj_val,
                                                    cur_len, w_ws, sw_ws);
    edge_z_kernel<<<dim3(B, SEG), 512, 0, stream>>>(adj_row, adj_col, adj_val,
                                                    w_ws, z_ws);
    gather_kernel<<<dim3(B, CH), 256, 0, stream>>>(neighbors, emb_table, z_ws, u_ws);
    head_kernel<<<B, 1024, 0, stream>>>(u_ws, sw_ws, W1, b1, W2, b2,
                                        fc1_w, fc1_b, cur_len, out);
}

// Round 4
// 226.955 us; speedup vs baseline: 1.5190x; 1.0218x over previous
//
#include <hip/hip_runtime.h>

#define B 64
#define N 2048
#define E 32768
#define D 256
#define H 256
#define CH 32          // gather chunks per batch (64 rows per block)
#define SEG 8          // edge segments per batch
#define EPB (E / SEG)  // 4096 edges per block

// ---------------------------------------------------------------------------
// Edge pass 1: w_part[b,seg,n] = sum_{e in seg: row<L, col==n} val[e]
// LDS histogram, then full coalesced float4 store of all 2048 bins.
// No global atomics, no zero-init needed downstream.
// ---------------------------------------------------------------------------
__global__ __launch_bounds__(512) void edge_w_kernel(
    const int* __restrict__ adj_row, const int* __restrict__ adj_col,
    const float* __restrict__ adj_val, const int* __restrict__ cur_len,
    float* __restrict__ w_part)
{
    __shared__ float wloc[N];
    const int b = blockIdx.x, seg = blockIdx.y, tid = threadIdx.x;
    const int L = *cur_len;

    for (int i = tid; i < N; i += 512) wloc[i] = 0.f;
    __syncthreads();

    const int base = b * E + seg * EPB;
    #pragma unroll
    for (int k = 0; k < EPB / 512; ++k) {
        const int e = base + tid + k * 512;
        const int r = adj_row[e];
        if (r < L) atomicAdd(&wloc[adj_col[e]], adj_val[e]);
    }
    __syncthreads();

    // coalesced flush: 512 threads x 1 float4 = 8KB
    float4* dst = (float4*)(w_part + ((size_t)b * SEG + seg) * N);
    const float4* src = (const float4*)wloc;
    dst[tid] = src[tid];
}

// ---------------------------------------------------------------------------
// Edge pass 2: rebuild full w[b,:] in LDS from the 8 partials, then
//   z_part[b,seg,m] = sum_{e in seg: col==m} w[row[e]] * val[e]
// seg==0 block also writes sw[b] = sum_n w[b,n].
// ---------------------------------------------------------------------------
__global__ __launch_bounds__(512) void edge_z_kernel(
    const int* __restrict__ adj_row, const int* __restrict__ adj_col,
    const float* __restrict__ adj_val, const float* __restrict__ w_part,
    float* __restrict__ z_part, float* __restrict__ sw_out)
{
    __shared__ float wfull[N];
    __shared__ float zloc[N];
    __shared__ float sred[8];
    const int b = blockIdx.x, seg = blockIdx.y, tid = threadIdx.x;

    // sum the 8 segment partials -> full w for this batch (64KB, L2/L3-hit)
    float swp = 0.f;
    for (int i = tid; i < N; i += 512) {
        float s = 0.f;
        #pragma unroll
        for (int sg = 0; sg < SEG; ++sg)
            s += w_part[((size_t)b * SEG + sg) * N + i];
        wfull[i] = s;
        zloc[i] = 0.f;
        swp += s;
    }
    __syncthreads();

    if (seg == 0) {   // one block per batch owns sw
        for (int off = 32; off; off >>= 1) swp += __shfl_down(swp, off, 64);
        if ((tid & 63) == 0) sred[tid >> 6] = swp;
    }
    __syncthreads();
    if (seg == 0 && tid == 0) {
        float s = 0.f;
        #pragma unroll
        for (int i = 0; i < 8; ++i) s += sred[i];
        sw_out[b] = s;
    }

    const int base = b * E + seg * EPB;
    #pragma unroll
    for (int k = 0; k < EPB / 512; ++k) {
        const int e = base + tid + k * 512;
        const float wv = wfull[adj_row[e]];
        if (wv != 0.f) atomicAdd(&zloc[adj_col[e]], wv * adj_val[e]);
    }
    __syncthreads();

    float4* dst = (float4*)(z_part + ((size_t)b * SEG + seg) * N);
    const float4* src = (const float4*)zloc;
    dst[tid] = src[tid];
}

// ---------------------------------------------------------------------------
// Gather: u_part[b,chunk,:] = sum_{n in chunk} z[b,n] * emb[neighbors[b,n],:]
// z[b,n] summed from z_part on the fly. Indices + z staged to LDS first so
// the fully-unrolled row loop has independent, immediately-computable
// addresses (no pointer-chase). One wave per row: lane = float4 offset.
// ---------------------------------------------------------------------------
__global__ __launch_bounds__(256) void gather_kernel(
    const int* __restrict__ neighbors, const float* __restrict__ emb,
    const float* __restrict__ z_part, float* __restrict__ u_part)
{
    const int b = blockIdx.x, chunk = blockIdx.y, tid = threadIdx.x;
    const int lane = tid & 63, rg = tid >> 6;
    const int n0 = chunk * (N / CH);          // 64 rows per block

    __shared__ float zs[N / CH];
    __shared__ int   ns[N / CH];
    if (tid < N / CH) {
        float s = 0.f;
        #pragma unroll
        for (int sg = 0; sg < SEG; ++sg)
            s += z_part[((size_t)b * SEG + sg) * N + n0 + tid];
        zs[tid] = s;
        ns[tid] = neighbors[(size_t)b * N + n0 + tid];
    }
    __syncthreads();

    const float4* __restrict__ emb4 = (const float4*)emb;
    float4 a0 = make_float4(0.f,0.f,0.f,0.f), a1 = a0, a2 = a0, a3 = a0;

    #pragma unroll
    for (int i = 0; i < 16; ++i) {            // 16 rows per wave
        const int j = i * 4 + rg;
        const float zv = zs[j];
        const size_t idx = (size_t)ns[j];
        const float4 v = emb4[idx * (D / 4) + lane];
        if ((i & 3) == 0)      { a0.x += zv*v.x; a0.y += zv*v.y; a0.z += zv*v.z; a0.w += zv*v.w; }
        else if ((i & 3) == 1) { a1.x += zv*v.x; a1.y += zv*v.y; a1.z += zv*v.z; a1.w += zv*v.w; }
        else if ((i & 3) == 2) { a2.x += zv*v.x; a2.y += zv*v.y; a2.z += zv*v.z; a2.w += zv*v.w; }
        else                   { a3.x += zv*v.x; a3.y += zv*v.y; a3.z += zv*v.z; a3.w += zv*v.w; }
    }
    float4 acc = make_float4(a0.x+a1.x+a2.x+a3.x, a0.y+a1.y+a2.y+a3.y,
                             a0.z+a1.z+a2.z+a3.z, a0.w+a1.w+a2.w+a3.w);

    __shared__ float4 red[256];
    red[tid] = acc;
    __syncthreads();
    if (tid < 64) {
        float4 a = red[tid], bb = red[tid + 64], c = red[tid + 128], d = red[tid + 192];
        float4 s = make_float4(a.x + bb.x + c.x + d.x, a.y + bb.y + c.y + d.y,
                               a.z + bb.z + c.z + d.z, a.w + bb.w + c.w + d.w);
        ((float4*)u_part)[((size_t)b * CH + chunk) * (D / 4) + tid] = s;
    }
}

// ---------------------------------------------------------------------------
// Head: u = sum_chunks u_part ; y = u@W1 + sw*b1 ; p = y@W2/L + b2 ;
//       out = relu(p@fc1_w + fc1_b).
// 1024 threads: t = output col, s = 4-way k-split (serial chain 256 -> 64).
// ---------------------------------------------------------------------------
__global__ __launch_bounds__(1024) void head_kernel(
    const float* __restrict__ u_part, const float* __restrict__ sw,
    const float* __restrict__ W1, const float* __restrict__ b1,
    const float* __restrict__ W2, const float* __restrict__ b2,
    const float* __restrict__ fc1_w, const float* __restrict__ fc1_b,
    const int* __restrict__ cur_len, float* __restrict__ out)
{
    const int b = blockIdx.x;
    const int t = threadIdx.x & 255;   // output column
    const int s = threadIdx.x >> 8;    // k-split group (0..3)
    __shared__ float red[4][256];
    __shared__ float su[D];
    __shared__ float sy[H];
    __shared__ float sp[H];

    float part = 0.f;
    #pragma unroll
    for (int c = 0; c < 8; ++c)
        part += u_part[((size_t)b * CH + s * 8 + c) * D + t];
    red[s][t] = part;
    __syncthreads();
    if (s == 0) su[t] = red[0][t] + red[1][t] + red[2][t] + red[3][t];
    __syncthreads();

    part = 0.f;
    #pragma unroll 8
    for (int k = 0; k < 64; ++k) {
        const int d = s * 64 + k;
        part += su[d] * W1[d * H + t];
    }
    red[s][t] = part;
    __syncthreads();
    if (s == 0) sy[t] = red[0][t] + red[1][t] + red[2][t] + red[3][t] + sw[b] * b1[t];
    __syncthreads();

    const float invL = 1.f / (float)(*cur_len);
    part = 0.f;
    #pragma unroll 8
    for (int k = 0; k < 64; ++k) {
        const int d = s * 64 + k;
        part += sy[d] * W2[d * H + t];
    }
    red[s][t] = part;
    __syncthreads();
    if (s == 0)
        sp[t] = (red[0][t] + red[1][t] + red[2][t] + red[3][t]) * invL + b2[t];
    __syncthreads();

    part = 0.f;
    #pragma unroll 8
    for (int k = 0; k < 64; ++k) {
        const int d = s * 64 + k;
        part += sp[d] * fc1_w[d * H + t];
    }
    red[s][t] = part;
    __syncthreads();
    if (s == 0) {
        const float v = red[0][t] + red[1][t] + red[2][t] + red[3][t] + fc1_b[t];
        out[(size_t)b * H + t] = fmaxf(v, 0.f);
    }
}

extern "C" void kernel_launch(void* const* d_in, const int* in_sizes, int n_in,
                              void* d_out, int out_size, void* d_ws, size_t ws_size,
                              hipStream_t stream) {
    const int*   neighbors = (const int*)  d_in[0];
    const int*   adj_row   = (const int*)  d_in[1];
    const int*   adj_col   = (const int*)  d_in[2];
    const float* adj_val   = (const float*)d_in[3];
    const float* emb_table = (const float*)d_in[4];
    const float* W1        = (const float*)d_in[5];
    const float* b1        = (const float*)d_in[6];
    const float* W2        = (const float*)d_in[7];
    const float* b2        = (const float*)d_in[8];
    const float* fc1_w     = (const float*)d_in[9];
    const float* fc1_b     = (const float*)d_in[10];
    const int*   cur_len   = (const int*)  d_in[11];
    float*       out       = (float*)d_out;

    // workspace layout (floats), all fully overwritten every call (no memset):
    // [w_part: B*SEG*N][z_part: B*SEG*N][sw: 64][u_part: B*CH*D]
    float* wp_ws = (float*)d_ws;
    float* zp_ws = wp_ws + (size_t)B * SEG * N;
    float* sw_ws = zp_ws + (size_t)B * SEG * N;
    float* u_ws  = sw_ws + 64;                 // 16B-aligned

    edge_w_kernel<<<dim3(B, SEG), 512, 0, stream>>>(adj_row, adj_col, adj_val,
                                                    cur_len, wp_ws);
    edge_z_kernel<<<dim3(B, SEG), 512, 0, stream>>>(adj_row, adj_col, adj_val,
                                                    wp_ws, zp_ws, sw_ws);
    gather_kernel<<<dim3(B, CH), 256, 0, stream>>>(neighbors, emb_table, zp_ws, u_ws);
    head_kernel<<<B, 1024, 0, stream>>>(u_ws, sw_ws, W1, b1, W2, b2,
                                        fc1_w, fc1_b, cur_len, out);
}